// Round 12
// baseline (116.867 us; speedup 1.0000x reference)
//
#include <hip/hip_runtime.h>
#include <math.h>

#define NC 16
#define DIM 16
#define LAYERS 6

typedef float v2f __attribute__((ext_vector_type(2)));

// ws layout (floats)
#define WS_LINV  0      // [NC][DIM][DIM] row-major, zeros above diag, 4096
#define WS_CST   4096   // [NC], 16
#define WS_ALPHA 4112   // [L][NC] = exp(log_alpha), 96
#define WS_DZ0   4208   // [L][NC][DIM]: z0_l - z0_{l+1} (l<5), z0_5 - mean (l=5)
#define WS_TOT   5744

// One block per component, one wave per block.
__global__ void __launch_bounds__(64) prep_kernel(
    const float* __restrict__ cov, const float* __restrict__ log_alpha,
    const float* __restrict__ z0, const float* __restrict__ mean,
    float* __restrict__ ws) {
    __shared__ float A[DIM * 17];     // padded: A[i][j] at i*17+j
    const int c = blockIdx.x;
    const int t = threadIdx.x;        // 0..63
    for (int k = t; k < DIM * DIM; k += 64) {
        int r = k >> 4, j = k & 15;
        A[r * 17 + j] = cov[c * 256 + k];
    }
    __syncthreads();
    const int i = t & 15;
    const bool act = t < 16;
    for (int k = 0; k < DIM; ++k) {
        if (act && i == k) A[k * 17 + k] = sqrtf(A[k * 17 + k]);
        __syncthreads();
        if (act && i > k) A[i * 17 + k] /= A[k * 17 + k];
        __syncthreads();
        if (act && i > k) {
            float lik = A[i * 17 + k];
            for (int j2 = k + 1; j2 <= i; ++j2)
                A[i * 17 + j2] -= lik * A[j2 * 17 + k];
        }
        __syncthreads();
    }
    // Forward substitution for column j of Linv — fully unrolled (VGPRs).
    const int j = i;
    float x[DIM];
    #pragma unroll
    for (int r = 0; r < DIM; ++r) {
        float s = (r == j) ? 1.0f : 0.0f;
        #pragma unroll
        for (int k = 0; k < r; ++k) s = fmaf(-A[r * 17 + k], x[k], s);
        x[r] = s / A[r * 17 + r];
    }
    if (act) {
        #pragma unroll
        for (int r = 0; r < DIM; ++r)
            ws[WS_LINV + c * 256 + r * 16 + j] = x[r];   // 0 above diag
    }
    if (t == 0) {
        float hld = 0.0f;
        #pragma unroll
        for (int r = 0; r < DIM; ++r) hld += __logf(A[r * 17 + r]);
        const float log2pi = 1.8378770664093453f;
        ws[WS_CST + c] = -0.5f * (float)DIM * log2pi - hld;
    }
    if (t < LAYERS) ws[WS_ALPHA + t * NC + c] = __expf(log_alpha[t * NC + c]);
    // dz0[l][c][i]: the d-state recurrence constant.
    if (act) {
        #pragma unroll
        for (int l = 0; l < LAYERS; ++l) {
            float cur = z0[(l * NC + c) * DIM + i];
            float nxt = (l < LAYERS - 1) ? z0[((l + 1) * NC + c) * DIM + i]
                                         : mean[c * DIM + i];
            ws[WS_DZ0 + (l * NC + c) * DIM + i] = cur - nxt;
        }
    }
}

// R11 + deferred single-log: the Jacobian is accumulated as a running
// product P = prod_l g_l^15 * (1+t2_l) (8 muls/layer via g^2,g^4,g^8
// squarings) with ONE v_log at the end — removes 12 of 24 trans-ops per
// thread from the quarter-rate trans pipe, where 8 in-phase waves/SIMD
// convoy (R9/R11: 27% idle issue despite full occupancy).
// Range-safe: |beta|<=0.35, alpha>=0.7 => bh>-0.5 => every factor >0;
// P within [1e-10,1e8] — no overflow/underflow/sign loss.
__global__ void __launch_bounds__(256) density_kernel(
    const float* __restrict__ z, const float* __restrict__ z0,
    const float* __restrict__ beta, const float* __restrict__ ws,
    float* __restrict__ out, int N) {
    __shared__ float tile[64 * 5];
    const int tid = threadIdx.x;
    const int lane = tid & 63;
    const int wv = tid >> 6;                       // 0..3
    const int xb = blockIdx.x >> 2;                // sample tile
    const int cg = blockIdx.x & 3;                 // c-group
    const int c = __builtin_amdgcn_readfirstlane(cg * 4 + wv);
    const int s = xb * 64 + lane;
    const int sl = s < N ? s : N - 1;    // clamp; only final store is guarded

    // d_0 = z - z0_0
    v2f d2[8];
    {
        const float4* zp = (const float4*)(z + (size_t)sl * DIM);
        const v2f* z0p = (const v2f*)(z0 + c * DIM);         // layer 0, uniform
        float4 a0 = zp[0], a1 = zp[1], a2 = zp[2], a3 = zp[3];
        d2[0] = (v2f){a0.x, a0.y} - z0p[0]; d2[1] = (v2f){a0.z, a0.w} - z0p[1];
        d2[2] = (v2f){a1.x, a1.y} - z0p[2]; d2[3] = (v2f){a1.z, a1.w} - z0p[3];
        d2[4] = (v2f){a2.x, a2.y} - z0p[4]; d2[5] = (v2f){a2.z, a2.w} - z0p[5];
        d2[6] = (v2f){a3.x, a3.y} - z0p[6]; d2[7] = (v2f){a3.z, a3.w} - z0p[7];
    }

    float P = 1.0f;                      // running Jacobian product
    #pragma unroll
    for (int l = 0; l < LAYERS; ++l) {
        v2f r2a = (v2f){0.f, 0.f}, r2b = (v2f){0.f, 0.f};
        #pragma unroll
        for (int k = 0; k < 8; ++k) {
            if (k & 1) r2b = __builtin_elementwise_fma(d2[k], d2[k], r2b);
            else       r2a = __builtin_elementwise_fma(d2[k], d2[k], r2a);
        }
        v2f r2v = r2a + r2b;
        float r = __builtin_amdgcn_sqrtf(r2v.x + r2v.y);  // raw v_sqrt_f32
        float al = ws[WS_ALPHA + l * NC + c];             // uniform -> s_load
        float b  = beta[l * NC + c];                      // uniform -> s_load
        float h  = __builtin_amdgcn_rcpf(al + r);
        float bh = b * h;
        float g  = 1.0f + bh;
        float u  = 1.0f + fmaf(-(b * r * h), h, bh);      // 1 + bh - b*r*h*h
        // P *= g^15 * u  (8 muls; no logs)
        float gg2 = g * g;
        float gg4 = gg2 * gg2;
        float gg8 = gg4 * gg4;
        float g15 = gg8 * gg4 * gg2 * g;
        P *= g15 * u;
        // d <- g*d + dz0_l   (dz0 uniform -> s_load)
        const v2f* dz = (const v2f*)(ws + WS_DZ0 + (l * NC + c) * DIM);
        v2f g2v = (v2f){g, g};
        #pragma unroll
        for (int k = 0; k < 8; ++k)
            d2[k] = __builtin_elementwise_fma(g2v, d2[k], dz[k]);
    }

    // q = || Linv_c * d ||^2  (d = zc_6 - mean), packed over j.
    const v2f* Li2 = (const v2f*)(ws + WS_LINV + c * 256);  // row i: Li2[i*8+jj]
    float q = 0.0f;
    #pragma unroll
    for (int i = 0; i < DIM; ++i) {
        v2f acc2 = (v2f){0.f, 0.f};
        #pragma unroll
        for (int jj = 0; jj <= (i >> 1); ++jj)
            acc2 = __builtin_elementwise_fma(Li2[i * 8 + jj], d2[jj], acc2);
        float acc = acc2.x + acc2.y;
        q = fmaf(acc, acc, q);
    }

    const float ln2 = 0.6931471805599453f;
    float slj = __builtin_amdgcn_logf(P) * ln2;       // single log (log2*ln2)
    float res = ws[WS_CST + c] + fmaf(-0.5f, q, slj);
    if (res != res) res = -INFINITY;     // NaN -> -inf (reference semantics)

    // Transpose through LDS (4-c group) for merged stores.
    tile[lane * 5 + wv] = res;
    __syncthreads();
    const int srow = tid >> 2, col = tid & 3;
    const int gs = xb * 64 + srow;
    if (gs < N) out[(size_t)gs * NC + cg * 4 + col] = tile[srow * 5 + col];
}

extern "C" void kernel_launch(void* const* d_in, const int* in_sizes, int n_in,
                              void* d_out, int out_size, void* d_ws, size_t ws_size,
                              hipStream_t stream) {
    const float* z    = (const float*)d_in[0];
    const float* z0   = (const float*)d_in[1];
    const float* la   = (const float*)d_in[2];
    const float* beta = (const float*)d_in[3];
    const float* mean = (const float*)d_in[4];
    const float* cov  = (const float*)d_in[5];
    float* out = (float*)d_out;
    float* ws  = (float*)d_ws;
    const int N = in_sizes[0] / DIM;

    hipLaunchKernelGGL(prep_kernel, dim3(NC), dim3(64), 0, stream, cov, la, z0, mean, ws);
    const int nb = (N + 63) / 64;
    hipLaunchKernelGGL(density_kernel, dim3(nb * 4), dim3(256), 0, stream,
                       z, z0, beta, ws, out, N);
}

// Round 13
// 106.891 us; speedup vs baseline: 1.0933x; 1.0933x over previous
//
#include <hip/hip_runtime.h>
#include <math.h>

#define NC 16
#define DIM 16
#define LAYERS 6

typedef float v2f __attribute__((ext_vector_type(2)));

// ws layout (floats)
#define WS_LINV  0      // [NC][DIM][DIM] row-major, zeros above diag, 4096
#define WS_CST   4096   // [NC], 16
#define WS_ALPHA 4112   // [L][NC] = exp(log_alpha), 96
#define WS_DZ0   4208   // [L][NC][DIM]: z0_l - z0_{l+1} (l<5), z0_5 - mean (l=5)
#define WS_IDF   5744   // [NC]: 1.0 if cov_c == I (exact), else 0.0
#define WS_TOT   5760

// One block per component, one wave per block.
__global__ void __launch_bounds__(64) prep_kernel(
    const float* __restrict__ cov, const float* __restrict__ log_alpha,
    const float* __restrict__ z0, const float* __restrict__ mean,
    float* __restrict__ ws) {
    __shared__ float A[DIM * 17];     // padded: A[i][j] at i*17+j
    const int c = blockIdx.x;
    const int t = threadIdx.x;        // 0..63 (one wave)
    bool ok = true;
    for (int k = t; k < DIM * DIM; k += 64) {
        int r = k >> 4, j = k & 15;
        float v = cov[c * 256 + k];
        A[r * 17 + j] = v;
        ok &= (v == ((r == j) ? 1.0f : 0.0f));   // exact identity test
    }
    unsigned long long m = __ballot(ok);
    if (t == 0) ws[WS_IDF + c] = (m == ~0ULL) ? 1.0f : 0.0f;
    __syncthreads();
    const int i = t & 15;
    const bool act = t < 16;
    for (int k = 0; k < DIM; ++k) {
        if (act && i == k) A[k * 17 + k] = sqrtf(A[k * 17 + k]);
        __syncthreads();
        if (act && i > k) A[i * 17 + k] /= A[k * 17 + k];
        __syncthreads();
        if (act && i > k) {
            float lik = A[i * 17 + k];
            for (int j2 = k + 1; j2 <= i; ++j2)
                A[i * 17 + j2] -= lik * A[j2 * 17 + k];
        }
        __syncthreads();
    }
    // Forward substitution for column j of Linv — fully unrolled (VGPRs).
    const int j = i;
    float x[DIM];
    #pragma unroll
    for (int r = 0; r < DIM; ++r) {
        float s = (r == j) ? 1.0f : 0.0f;
        #pragma unroll
        for (int k = 0; k < r; ++k) s = fmaf(-A[r * 17 + k], x[k], s);
        x[r] = s / A[r * 17 + r];
    }
    if (act) {
        #pragma unroll
        for (int r = 0; r < DIM; ++r)
            ws[WS_LINV + c * 256 + r * 16 + j] = x[r];   // 0 above diag
    }
    if (t == 0) {
        float hld = 0.0f;
        #pragma unroll
        for (int r = 0; r < DIM; ++r) hld += __logf(A[r * 17 + r]);
        const float log2pi = 1.8378770664093453f;
        ws[WS_CST + c] = -0.5f * (float)DIM * log2pi - hld;
    }
    if (t < LAYERS) ws[WS_ALPHA + t * NC + c] = __expf(log_alpha[t * NC + c]);
    // dz0[l][c][i]: the d-state recurrence constant.
    if (act) {
        #pragma unroll
        for (int l = 0; l < LAYERS; ++l) {
            float cur = z0[(l * NC + c) * DIM + i];
            float nxt = (l < LAYERS - 1) ? z0[((l + 1) * NC + c) * DIM + i]
                                         : mean[c * DIM + i];
            ws[WS_DZ0 + (l * NC + c) * DIM + i] = cur - nxt;
        }
    }
}

// R12 + (a) running products Pg=prod(g), Pu=prod(u), two logs at the end
// (saves the 5-mul g^15 chain per layer; Pg,Pu within [4e-3,20] — safe,
// unlike Pg^15 which can graze denormals), and (b) an identity-covariance
// fast path: prep sets a per-c flag when cov_c == I exactly; then Linv=I
// and q = ||d||^2 — the 352-issue-cycle triangular matvec (36% of the
// kernel) collapses to an 8-pk reduction. General path retained; branch
// is wave-uniform scalar (readfirstlane), no divergence.
__global__ void __launch_bounds__(256) density_kernel(
    const float* __restrict__ z, const float* __restrict__ z0,
    const float* __restrict__ beta, const float* __restrict__ ws,
    float* __restrict__ out, int N) {
    __shared__ float tile[64 * 5];
    const int tid = threadIdx.x;
    const int lane = tid & 63;
    const int wv = tid >> 6;                       // 0..3
    const int xb = blockIdx.x >> 2;                // sample tile
    const int cg = blockIdx.x & 3;                 // c-group
    const int c = __builtin_amdgcn_readfirstlane(cg * 4 + wv);
    const int s = xb * 64 + lane;
    const int sl = s < N ? s : N - 1;    // clamp; only final store is guarded

    // d_0 = z - z0_0
    v2f d2[8];
    {
        const float4* zp = (const float4*)(z + (size_t)sl * DIM);
        const v2f* z0p = (const v2f*)(z0 + c * DIM);         // layer 0, uniform
        float4 a0 = zp[0], a1 = zp[1], a2 = zp[2], a3 = zp[3];
        d2[0] = (v2f){a0.x, a0.y} - z0p[0]; d2[1] = (v2f){a0.z, a0.w} - z0p[1];
        d2[2] = (v2f){a1.x, a1.y} - z0p[2]; d2[3] = (v2f){a1.z, a1.w} - z0p[3];
        d2[4] = (v2f){a2.x, a2.y} - z0p[4]; d2[5] = (v2f){a2.z, a2.w} - z0p[5];
        d2[6] = (v2f){a3.x, a3.y} - z0p[6]; d2[7] = (v2f){a3.z, a3.w} - z0p[7];
    }

    float Pg = 1.0f, Pu = 1.0f;          // running Jacobian products
    #pragma unroll
    for (int l = 0; l < LAYERS; ++l) {
        v2f r2a = (v2f){0.f, 0.f}, r2b = (v2f){0.f, 0.f};
        #pragma unroll
        for (int k = 0; k < 8; ++k) {
            if (k & 1) r2b = __builtin_elementwise_fma(d2[k], d2[k], r2b);
            else       r2a = __builtin_elementwise_fma(d2[k], d2[k], r2a);
        }
        v2f r2v = r2a + r2b;
        float r = __builtin_amdgcn_sqrtf(r2v.x + r2v.y);  // raw v_sqrt_f32
        float al = ws[WS_ALPHA + l * NC + c];             // uniform -> s_load
        float b  = beta[l * NC + c];                      // uniform -> s_load
        float h  = __builtin_amdgcn_rcpf(al + r);
        float bh = b * h;
        float g  = 1.0f + bh;
        float u  = 1.0f + fmaf(-(b * r * h), h, bh);      // 1 + bh - b*r*h*h
        Pg *= g;
        Pu *= u;
        // d <- g*d + dz0_l   (dz0 uniform -> s_load)
        const v2f* dz = (const v2f*)(ws + WS_DZ0 + (l * NC + c) * DIM);
        v2f g2v = (v2f){g, g};
        #pragma unroll
        for (int k = 0; k < 8; ++k)
            d2[k] = __builtin_elementwise_fma(g2v, d2[k], dz[k]);
    }

    // q: identity fast path (cov==I -> Linv=I -> q=||d||^2) or general
    // triangular matvec. Wave-uniform scalar branch.
    int idf = __builtin_amdgcn_readfirstlane((int)ws[WS_IDF + c]);
    float q;
    if (idf) {
        v2f qa = (v2f){0.f, 0.f}, qb = (v2f){0.f, 0.f};
        #pragma unroll
        for (int k = 0; k < 8; ++k) {
            if (k & 1) qb = __builtin_elementwise_fma(d2[k], d2[k], qb);
            else       qa = __builtin_elementwise_fma(d2[k], d2[k], qa);
        }
        v2f qv = qa + qb;
        q = qv.x + qv.y;
    } else {
        const v2f* Li2 = (const v2f*)(ws + WS_LINV + c * 256);
        q = 0.0f;
        #pragma unroll
        for (int i = 0; i < DIM; ++i) {
            v2f acc2 = (v2f){0.f, 0.f};
            #pragma unroll
            for (int jj = 0; jj <= (i >> 1); ++jj)
                acc2 = __builtin_elementwise_fma(Li2[i * 8 + jj], d2[jj], acc2);
            float acc = acc2.x + acc2.y;
            q = fmaf(acc, acc, q);
        }
    }

    const float ln2 = 0.6931471805599453f;
    float slj = fmaf(15.0f, __builtin_amdgcn_logf(Pg),
                     __builtin_amdgcn_logf(Pu)) * ln2;
    float res = ws[WS_CST + c] + fmaf(-0.5f, q, slj);
    if (res != res) res = -INFINITY;     // NaN -> -inf (reference semantics)

    // Transpose through LDS (4-c group) for merged stores.
    tile[lane * 5 + wv] = res;
    __syncthreads();
    const int srow = tid >> 2, col = tid & 3;
    const int gs = xb * 64 + srow;
    if (gs < N) out[(size_t)gs * NC + cg * 4 + col] = tile[srow * 5 + col];
}

extern "C" void kernel_launch(void* const* d_in, const int* in_sizes, int n_in,
                              void* d_out, int out_size, void* d_ws, size_t ws_size,
                              hipStream_t stream) {
    const float* z    = (const float*)d_in[0];
    const float* z0   = (const float*)d_in[1];
    const float* la   = (const float*)d_in[2];
    const float* beta = (const float*)d_in[3];
    const float* mean = (const float*)d_in[4];
    const float* cov  = (const float*)d_in[5];
    float* out = (float*)d_out;
    float* ws  = (float*)d_ws;
    const int N = in_sizes[0] / DIM;

    hipLaunchKernelGGL(prep_kernel, dim3(NC), dim3(64), 0, stream, cov, la, z0, mean, ws);
    const int nb = (N + 63) / 64;
    hipLaunchKernelGGL(density_kernel, dim3(nb * 4), dim3(256), 0, stream,
                       z, z0, beta, ws, out, N);
}